// Round 5
// baseline (167.113 us; speedup 1.0000x reference)
//
#include <hip/hip_runtime.h>

#define N_TOK 4096
#define BATCH 4

typedef __attribute__((ext_vector_type(8))) short short8;
typedef __attribute__((ext_vector_type(4))) float floatx4;

// Pack two floats to packed bf16 pair (round-half-away): 3 VALU ops.
__device__ __forceinline__ unsigned pack_rnd(float a, float b) {
    unsigned ra = __float_as_uint(a) + 0x8000u;
    unsigned rb = __float_as_uint(b) + 0x8000u;
    return __builtin_amdgcn_perm(rb, ra, 0x07060302u);
}

// Split two floats into bf16 hi-pair and lo-pair.
__device__ __forceinline__ void split_pack(float a, float b,
                                           unsigned &ph, unsigned &pl) {
    unsigned ra = __float_as_uint(a) + 0x8000u;
    unsigned rb = __float_as_uint(b) + 0x8000u;
    ph = __builtin_amdgcn_perm(rb, ra, 0x07060302u);
    float la = a - __uint_as_float(ra & 0xffff0000u);
    float lb = b - __uint_as_float(rb & 0xffff0000u);
    pl = __builtin_amdgcn_perm(__float_as_uint(lb) + 0x8000u,
                               __float_as_uint(la) + 0x8000u, 0x07060302u);
}

__device__ __forceinline__ short8 mk_short8(unsigned p0, unsigned p1,
                                            unsigned p2, unsigned p3) {
    union { unsigned u[4]; short8 s; } c;
    c.u[0] = p0; c.u[1] = p1; c.u[2] = p2; c.u[3] = p3;
    return c.s;
}

// Convert 8 consecutive fp32 (two float4) into hi/lo short8 fragments.
__device__ __forceinline__ void cvt_frag(const float* src,
                                         short8 &hi, short8 &lo) {
    float4 w0 = *(const float4*)src;
    float4 w1 = *(const float4*)(src + 4);
    unsigned ph[4], pl[4];
    split_pack(w0.x, w0.y, ph[0], pl[0]);
    split_pack(w0.z, w0.w, ph[1], pl[1]);
    split_pack(w1.x, w1.y, ph[2], pl[2]);
    split_pack(w1.z, w1.w, ph[3], pl[3]);
    hi = mk_short8(ph[0], ph[1], ph[2], ph[3]);
    lo = mk_short8(pl[0], pl[1], pl[2], pl[3]);
}

__device__ __forceinline__ float fast_exp2(float x) {
#if __has_builtin(__builtin_amdgcn_exp2f)
    return __builtin_amdgcn_exp2f(x);
#else
    return exp2f(x);
#endif
}

// ---------------------------------------------------------------------------
// QKV GEMM, fully LDS-staged operands.  (round-3 proven form)
// ---------------------------------------------------------------------------
__global__ __launch_bounds__(256) void gemm1_fused(
    const float* __restrict__ wq, const float* __restrict__ x,
    unsigned short* __restrict__ Qp, unsigned short* __restrict__ Kp,
    unsigned short* __restrict__ Vp)
{
    const int N = N_TOK;
    const int b = blockIdx.z;
    const int row0 = blockIdx.y * 64;
    const int col0 = blockIdx.x * 64;
    const int t = threadIdx.x;
    const int wave = t >> 6, lane = t & 63;
    const int l16 = lane & 15, quad = lane >> 4;
    const int msub0 = (wave & 1) * 32, nsub0 = (wave >> 1) * 32;

    __shared__ __align__(16) char smem[29184];
    float (*Xf)[68] = (float(*)[68])smem;                      // [32][68] 8704B
    unsigned short* XsH = (unsigned short*)(smem + 8704);      // [64][40]
    unsigned short* XsL = (unsigned short*)(smem + 13824);
    unsigned short* WsH = (unsigned short*)(smem + 18944);
    unsigned short* WsL = (unsigned short*)(smem + 24064);

    floatx4 acc[2][2] = {};

    const int xr = t >> 3, xnb = (t & 7) * 8;      // x load role
    const int tnr = t >> 2, tkb = (t & 3) * 8;     // x transpose role
    const int wm = t >> 2, wk = (t & 3) * 8;       // W load/convert role

    for (int kc = 0; kc < 8; ++kc) {
        __syncthreads();
        {   // W chunk: coalesced load + in-reg split -> LDS [m][40] hi/lo
            const float* wsrc = wq + (size_t)(row0 + wm) * 256 + kc * 32 + wk;
            float4 w0 = *(const float4*)wsrc;
            float4 w1 = *(const float4*)(wsrc + 4);
            unsigned ph[4], pl[4];
            split_pack(w0.x, w0.y, ph[0], pl[0]);
            split_pack(w0.z, w0.w, ph[1], pl[1]);
            split_pack(w1.x, w1.y, ph[2], pl[2]);
            split_pack(w1.z, w1.w, ph[3], pl[3]);
            *(uint4*)(WsH + wm * 40 + wk) = *(uint4*)ph;
            *(uint4*)(WsL + wm * 40 + wk) = *(uint4*)pl;
        }
        {   // x chunk: coalesced fp32 -> Xf
            const float* src = x + ((size_t)b * 256 + kc * 32 + xr) * N + col0 + xnb;
            *(float4*)&Xf[xr][xnb]     = *(const float4*)src;
            *(float4*)&Xf[xr][xnb + 4] = *(const float4*)(src + 4);
        }
        __syncthreads();
        {   // transpose+split x -> [n][40] hi/lo
            unsigned ph[4], pl[4];
#pragma unroll
            for (int q = 0; q < 4; ++q)
                split_pack(Xf[tkb + 2 * q][tnr], Xf[tkb + 2 * q + 1][tnr],
                           ph[q], pl[q]);
            *(uint4*)(XsH + tnr * 40 + tkb) = *(uint4*)ph;
            *(uint4*)(XsL + tnr * 40 + tkb) = *(uint4*)pl;
        }
        __syncthreads();
        short8 ah0 = *(const short8*)(WsH + (msub0 + l16) * 40 + quad * 8);
        short8 ah1 = *(const short8*)(WsH + (msub0 + 16 + l16) * 40 + quad * 8);
        short8 al0 = *(const short8*)(WsL + (msub0 + l16) * 40 + quad * 8);
        short8 al1 = *(const short8*)(WsL + (msub0 + 16 + l16) * 40 + quad * 8);
        short8 bh0 = *(const short8*)(XsH + (nsub0 + l16) * 40 + quad * 8);
        short8 bh1 = *(const short8*)(XsH + (nsub0 + 16 + l16) * 40 + quad * 8);
        short8 bl0 = *(const short8*)(XsL + (nsub0 + l16) * 40 + quad * 8);
        short8 bl1 = *(const short8*)(XsL + (nsub0 + 16 + l16) * 40 + quad * 8);
        acc[0][0] = __builtin_amdgcn_mfma_f32_16x16x32_bf16(ah0, bh0, acc[0][0], 0, 0, 0);
        acc[0][1] = __builtin_amdgcn_mfma_f32_16x16x32_bf16(ah0, bh1, acc[0][1], 0, 0, 0);
        acc[1][0] = __builtin_amdgcn_mfma_f32_16x16x32_bf16(ah1, bh0, acc[1][0], 0, 0, 0);
        acc[1][1] = __builtin_amdgcn_mfma_f32_16x16x32_bf16(ah1, bh1, acc[1][1], 0, 0, 0);
        acc[0][0] = __builtin_amdgcn_mfma_f32_16x16x32_bf16(ah0, bl0, acc[0][0], 0, 0, 0);
        acc[0][1] = __builtin_amdgcn_mfma_f32_16x16x32_bf16(ah0, bl1, acc[0][1], 0, 0, 0);
        acc[1][0] = __builtin_amdgcn_mfma_f32_16x16x32_bf16(ah1, bl0, acc[1][0], 0, 0, 0);
        acc[1][1] = __builtin_amdgcn_mfma_f32_16x16x32_bf16(ah1, bl1, acc[1][1], 0, 0, 0);
        acc[0][0] = __builtin_amdgcn_mfma_f32_16x16x32_bf16(al0, bh0, acc[0][0], 0, 0, 0);
        acc[0][1] = __builtin_amdgcn_mfma_f32_16x16x32_bf16(al0, bh1, acc[0][1], 0, 0, 0);
        acc[1][0] = __builtin_amdgcn_mfma_f32_16x16x32_bf16(al1, bh0, acc[1][0], 0, 0, 0);
        acc[1][1] = __builtin_amdgcn_mfma_f32_16x16x32_bf16(al1, bh1, acc[1][1], 0, 0, 0);
    }

    __syncthreads();
    const int region = row0 >> 7;   // 0=Q, 1=K, 2=V
    if (region == 2) {
        float (*LdsF)[68] = (float(*)[68])smem;
#pragma unroll
        for (int i = 0; i < 2; ++i)
#pragma unroll
            for (int j = 0; j < 2; ++j) {
                const int m = msub0 + i * 16 + quad * 4;
                const int n = nsub0 + j * 16 + l16;
#pragma unroll
                for (int r = 0; r < 4; ++r) LdsF[m + r][n] = acc[i][j][r];
            }
        __syncthreads();
        const int m = t >> 2, nb2 = (t & 3) * 16;
        const int vrow = b * 128 + (row0 - 256) + m;
        unsigned pk[8];
#pragma unroll
        for (int q = 0; q < 8; ++q)
            pk[q] = pack_rnd(LdsF[m][nb2 + 2 * q], LdsF[m][nb2 + 2 * q + 1]);
        unsigned short* dst = Vp + (size_t)vrow * N + col0 + nb2;
        *(uint4*)&dst[0] = *(uint4*)&pk[0];
        *(uint4*)&dst[8] = *(uint4*)&pk[4];
    } else {
        unsigned short (*LdsT)[68] = (unsigned short(*)[68])smem;
        const float sc = region ? 1.0f
                                : (0.17677669529663687f * 1.4426950408889634f);
#pragma unroll
        for (int i = 0; i < 2; ++i)
#pragma unroll
            for (int j = 0; j < 2; ++j) {
                const int m = msub0 + i * 16 + quad * 4;
                const int n = nsub0 + j * 16 + l16;
                uint2 pr;
                pr.x = pack_rnd(acc[i][j][0] * sc, acc[i][j][1] * sc);
                pr.y = pack_rnd(acc[i][j][2] * sc, acc[i][j][3] * sc);
                *(uint2*)&LdsT[n][m] = pr;
            }
        __syncthreads();
        const int n = t & 63, hb = (t >> 6) & 1, dh = t >> 7;
        const int h = ((row0 & 127) >> 5) + hb;
        const int m0 = hb * 32 + dh * 16;
        unsigned tmp[8];
        *(uint2*)&tmp[0] = *(const uint2*)&LdsT[n][m0];
        *(uint2*)&tmp[2] = *(const uint2*)&LdsT[n][m0 + 4];
        *(uint2*)&tmp[4] = *(const uint2*)&LdsT[n][m0 + 8];
        *(uint2*)&tmp[6] = *(const uint2*)&LdsT[n][m0 + 12];
        unsigned short* dst = (region ? Kp : Qp) +
            ((size_t)(b * 4 + h) * N + col0 + n) * 32 + dh * 16;
        *(uint4*)&dst[0] = *(uint4*)&tmp[0];
        *(uint4*)&dst[8] = *(uint4*)&tmp[4];
    }
}

// ---------------------------------------------------------------------------
// MFMA flash attention, Q-TILE 64 (was 128): grid (64 i0, 16 bh) = 1024
// blocks = 4 blocks/CU (was 512 = 2/CU; occupancy was the binding limit:
// 31% with every pipe <60%).  512 threads = two 4-wave teams (keys split
// 0..2047 / 2048..4095), each wave owns 16 q-rows (g-loop removed).
// Staging/K-slot-interleave/V layout/per-q accumulation order UNCHANGED ->
// numerics bit-identical to round 3 (absmax must be 3.051758e-05).
// LDS 38912 B.
// ---------------------------------------------------------------------------
__global__ __launch_bounds__(512) void attn_fused(
    const unsigned short* __restrict__ Qp,
    const unsigned short* __restrict__ Kp,
    const unsigned short* __restrict__ Vp,
    unsigned short* __restrict__ Oth, unsigned short* __restrict__ Otl)
{
    const int N = N_TOK;
    const int bh = blockIdx.y;
    const int b = bh >> 2, h = bh & 3;
    const int i0 = blockIdx.x * 64;
    const int t = threadIdx.x;
    const int wave = t >> 6, lane = t & 63;
    const int l16 = lane & 15, quad = lane >> 4;
    const int team = wave >> 2, w4 = wave & 3;

    __shared__ __align__(16) char smem[38912];
    unsigned short* S = (unsigned short*)smem;

    short8 ones;
#pragma unroll
    for (int e = 0; e < 8; ++e) ones[e] = (short)0x3F80;

    // single 16-row Q fragment per wave
    short8 qh = *(const short8*)(Qp +
        ((size_t)bh * N + i0 + w4 * 16 + l16) * 32 + quad * 8);

    floatx4 o[2] = {};
    floatx4 lacc = {};

    // staging: threads 0..255 stage K (both teams), 256..511 stage V
    const int st_k = t & 255;
    const int skey = st_k >> 2, sdp = (st_k & 3) * 8;
    // interleaved K row slot: key = 32ks+8q+4b+r -> slot = 32ks+16b+4q+r
    const int sslot = (skey & 32) | ((skey & 4) << 2) | ((skey & 24) >> 1)
                    | (skey & 3);
    const int svd = st_k >> 3, svp = (st_k & 7) * 8;
    const unsigned short* kp0 = Kp + ((size_t)bh * N + skey) * 32 + sdp;
    const unsigned short* kp1 = kp0 + (size_t)2048 * 32;
    const unsigned short* vp0 = Vp + ((size_t)bh * 32 + svd) * N + svp;
    const unsigned short* vp1 = vp0 + 2048;

    short8 r0, r1;
    if (t < 256) { r0 = *(const short8*)kp0; r1 = *(const short8*)kp1; }
    else         { r0 = *(const short8*)vp0; r1 = *(const short8*)vp1; }
    if (t < 256) {
        *(short8*)(S + sslot * 40 + sdp) = r0;
        *(short8*)(S + 2560 + sslot * 40 + sdp) = r1;
    } else {
        *(short8*)(S + 10240 + svd * 72 + svp) = r0;
        *(short8*)(S + 10240 + 2304 + svd * 72 + svp) = r1;
    }
    kp0 += 64 * 32; kp1 += 64 * 32; vp0 += 64; vp1 += 64;
    if (t < 256) { r0 = *(const short8*)kp0; r1 = *(const short8*)kp1; }
    else         { r0 = *(const short8*)vp0; r1 = *(const short8*)vp1; }
    __syncthreads();

    for (int it = 0; it < 32; ++it) {
        const int cur = it & 1;
        if (it + 1 < 32) {
            const int nb = 1 - cur;
            if (t < 256) {
                *(short8*)(S + nb * 5120 + sslot * 40 + sdp) = r0;
                *(short8*)(S + nb * 5120 + 2560 + sslot * 40 + sdp) = r1;
            } else {
                *(short8*)(S + 10240 + nb * 4608 + svd * 72 + svp) = r0;
                *(short8*)(S + 10240 + nb * 4608 + 2304 + svd * 72 + svp) = r1;
            }
        }
        if (it + 2 < 32) {
            kp0 += 64 * 32; kp1 += 64 * 32; vp0 += 64; vp1 += 64;
            if (t < 256) { r0 = *(const short8*)kp0; r1 = *(const short8*)kp1; }
            else         { r0 = *(const short8*)vp0; r1 = *(const short8*)vp1; }
        }

        const unsigned short* Ksr = S + cur * 5120 + team * 2560;
        const unsigned short* Vsr = S + 10240 + cur * 4608 + team * 2304;

        short8 kh0 = *(const short8*)(Ksr + ( 0 + l16) * 40 + quad * 8);
        short8 kh1 = *(const short8*)(Ksr + (16 + l16) * 40 + quad * 8);
        short8 kh2 = *(const short8*)(Ksr + (32 + l16) * 40 + quad * 8);
        short8 kh3 = *(const short8*)(Ksr + (48 + l16) * 40 + quad * 8);
        short8 vh00 = *(const short8*)(Vsr + ( 0 + l16) * 72 +  0 + quad * 8);
        short8 vh01 = *(const short8*)(Vsr + (16 + l16) * 72 +  0 + quad * 8);
        short8 vh10 = *(const short8*)(Vsr + ( 0 + l16) * 72 + 32 + quad * 8);
        short8 vh11 = *(const short8*)(Vsr + (16 + l16) * 72 + 32 + quad * 8);

        const floatx4 z = {0.0f, 0.0f, 0.0f, 0.0f};
        floatx4 s0 = __builtin_amdgcn_mfma_f32_16x16x32_bf16(kh0, qh, z, 0, 0, 0);
        floatx4 s1 = __builtin_amdgcn_mfma_f32_16x16x32_bf16(kh1, qh, z, 0, 0, 0);
        floatx4 s2 = __builtin_amdgcn_mfma_f32_16x16x32_bf16(kh2, qh, z, 0, 0, 0);
        floatx4 s3 = __builtin_amdgcn_mfma_f32_16x16x32_bf16(kh3, qh, z, 0, 0, 0);
        // ks = 0 (keys 0..31): s0[r] = P[8q+r], s1[r] = P[8q+4+r]
        short8 pf0 = mk_short8(
            pack_rnd(fast_exp2(s0[0]), fast_exp2(s0[1])),
            pack_rnd(fast_exp2(s0[2]), fast_exp2(s0[3])),
            pack_rnd(fast_exp2(s1[0]), fast_exp2(s1[1])),
            pack_rnd(fast_exp2(s1[2]), fast_exp2(s1[3])));
        o[0] = __builtin_amdgcn_mfma_f32_16x16x32_bf16(vh00, pf0, o[0], 0, 0, 0);
        o[1] = __builtin_amdgcn_mfma_f32_16x16x32_bf16(vh01, pf0, o[1], 0, 0, 0);
        lacc = __builtin_amdgcn_mfma_f32_16x16x32_bf16(ones, pf0, lacc, 0, 0, 0);
        // ks = 1 (keys 32..63)
        short8 pf1 = mk_short8(
            pack_rnd(fast_exp2(s2[0]), fast_exp2(s2[1])),
            pack_rnd(fast_exp2(s2[2]), fast_exp2(s2[3])),
            pack_rnd(fast_exp2(s3[0]), fast_exp2(s3[1])),
            pack_rnd(fast_exp2(s3[2]), fast_exp2(s3[3])));
        o[0] = __builtin_amdgcn_mfma_f32_16x16x32_bf16(vh10, pf1, o[0], 0, 0, 0);
        o[1] = __builtin_amdgcn_mfma_f32_16x16x32_bf16(vh11, pf1, o[1], 0, 0, 0);
        lacc = __builtin_amdgcn_mfma_f32_16x16x32_bf16(ones, pf1, lacc, 0, 0, 0);
        __syncthreads();
    }

    // ---- epilogue: cross-team combine, normalize, transpose, split ----
    float (*OfB)[68] = (float(*)[68])smem;                  // [32][68] team1 O^T
    float* Lb = (float*)(smem + 8704);                      // [64] team1 l
    float (*OfA)[68] = (float(*)[68])(smem + 8960);         // [32][68] final

    if (team == 1) {
        const int q = w4 * 16 + l16;
#pragma unroll
        for (int half = 0; half < 2; ++half)
#pragma unroll
            for (int r = 0; r < 4; ++r)
                OfB[half * 16 + quad * 4 + r][q] = o[half][r];
        if (quad == 0) Lb[q] = lacc[0];
    }
    __syncthreads();
    if (team == 0) {
        const int q = w4 * 16 + l16;
        const float inv = 1.0f / (lacc[0] + Lb[q]);
#pragma unroll
        for (int half = 0; half < 2; ++half)
#pragma unroll
            for (int r = 0; r < 4; ++r) {
                const int d = half * 16 + quad * 4 + r;
                OfA[d][q] = (o[half][r] + OfB[d][q]) * inv;
            }
    }
    __syncthreads();
    {
        const int q = t >> 3, db = (t & 7) * 4;
        unsigned ph[2], pl[2];
#pragma unroll
        for (int i = 0; i < 2; ++i)
            split_pack(OfA[db + 2 * i][q], OfA[db + 2 * i + 1][q], ph[i], pl[i]);
        const size_t off = ((size_t)b * N + i0 + q) * 128 + h * 32 + db;
        *(uint2*)(Oth + off) = *(uint2*)ph;
        *(uint2*)(Otl + off) = *(uint2*)pl;
    }
}

// ---------------------------------------------------------------------------
// Output GEMM, split-bf16 MFMA, LDS-staged B, inline-converted W (preloaded),
// + bias.  (round-3 proven form)
// ---------------------------------------------------------------------------
__global__ __launch_bounds__(256) void gemm2_fused(
    const float* __restrict__ wo,
    const unsigned short* __restrict__ Oth, const unsigned short* __restrict__ Otl,
    const float* __restrict__ bias, float* __restrict__ y)
{
    const int N = N_TOK;
    const int b = blockIdx.z;
    const int row0 = blockIdx.y * 64;
    const int col0 = blockIdx.x * 64;
    const int t = threadIdx.x;
    const int wave = t >> 6, lane = t & 63;
    const int l16 = lane & 15, quad = lane >> 4;
    const int msub0 = (wave & 1) * 32, nsub0 = (wave >> 1) * 32;

    __shared__ __align__(16) char smem[17408];
    unsigned short* BsH = (unsigned short*)smem;           // [64][40]
    unsigned short* BsL = (unsigned short*)(smem + 5120);  // [64][40]
    float (*LdsF)[68] = (float(*)[68])smem;                // epilogue reuse

    short8 ah[4][2], al[4][2];
#pragma unroll
    for (int kc = 0; kc < 4; ++kc)
#pragma unroll
        for (int r = 0; r < 2; ++r)
            cvt_frag(wo + (size_t)(row0 + msub0 + r * 16 + l16) * 128 +
                         kc * 32 + quad * 8,
                     ah[kc][r], al[kc][r]);

    const int srow = t >> 2, sk = (t & 3) * 8;
    const unsigned short* gH = Oth + ((size_t)b * N + col0 + srow) * 128 + sk;
    const unsigned short* gL = Otl + ((size_t)b * N + col0 + srow) * 128 + sk;

    floatx4 acc[2][2] = {};
#pragma unroll
    for (int kc = 0; kc < 4; ++kc) {
        short8 hreg = *(const short8*)(gH + kc * 32);
        short8 lreg = *(const short8*)(gL + kc * 32);
        __syncthreads();
        *(short8*)(BsH + srow * 40 + sk) = hreg;
        *(short8*)(BsL + srow * 40 + sk) = lreg;
        __syncthreads();
        short8 bh0 = *(const short8*)(BsH + (nsub0 + l16) * 40 + quad * 8);
        short8 bh1 = *(const short8*)(BsH + (nsub0 + 16 + l16) * 40 + quad * 8);
        short8 bl0 = *(const short8*)(BsL + (nsub0 + l16) * 40 + quad * 8);
        short8 bl1 = *(const short8*)(BsL + (nsub0 + 16 + l16) * 40 + quad * 8);
        acc[0][0] = __builtin_amdgcn_mfma_f32_16x16x32_bf16(ah[kc][0], bh0, acc[0][0], 0, 0, 0);
        acc[0][1] = __builtin_amdgcn_mfma_f32_16x16x32_bf16(ah[kc][0], bh1, acc[0][1], 0, 0, 0);
        acc[1][0] = __builtin_amdgcn_mfma_f32_16x16x32_bf16(ah[kc][1], bh0, acc[1][0], 0, 0, 0);
        acc[1][1] = __builtin_amdgcn_mfma_f32_16x16x32_bf16(ah[kc][1], bh1, acc[1][1], 0, 0, 0);
        acc[0][0] = __builtin_amdgcn_mfma_f32_16x16x32_bf16(ah[kc][0], bl0, acc[0][0], 0, 0, 0);
        acc[0][1] = __builtin_amdgcn_mfma_f32_16x16x32_bf16(ah[kc][0], bl1, acc[0][1], 0, 0, 0);
        acc[1][0] = __builtin_amdgcn_mfma_f32_16x16x32_bf16(ah[kc][1], bl0, acc[1][0], 0, 0, 0);
        acc[1][1] = __builtin_amdgcn_mfma_f32_16x16x32_bf16(ah[kc][1], bl1, acc[1][1], 0, 0, 0);
        acc[0][0] = __builtin_amdgcn_mfma_f32_16x16x32_bf16(al[kc][0], bh0, acc[0][0], 0, 0, 0);
        acc[0][1] = __builtin_amdgcn_mfma_f32_16x16x32_bf16(al[kc][0], bh1, acc[0][1], 0, 0, 0);
        acc[1][0] = __builtin_amdgcn_mfma_f32_16x16x32_bf16(al[kc][1], bh0, acc[1][0], 0, 0, 0);
        acc[1][1] = __builtin_amdgcn_mfma_f32_16x16x32_bf16(al[kc][1], bh1, acc[1][1], 0, 0, 0);
    }

    __syncthreads();
#pragma unroll
    for (int i = 0; i < 2; ++i)
#pragma unroll
        for (int j = 0; j < 2; ++j) {
            const int m = msub0 + i * 16 + quad * 4;
            const int n = nsub0 + j * 16 + l16;
#pragma unroll
            for (int r = 0; r < 4; ++r) LdsF[m + r][n] = acc[i][j][r];
        }
    __syncthreads();
    const int m = t >> 2, nb = (t & 3) * 16;
    const float bv = bias[row0 + m];
    float* dst = y + ((size_t)b * 256 + row0 + m) * N + col0 + nb;
#pragma unroll
    for (int g = 0; g < 4; ++g) {
        float4 o4;
        o4.x = LdsF[m][nb + g * 4 + 0] + bv;
        o4.y = LdsF[m][nb + g * 4 + 1] + bv;
        o4.z = LdsF[m][nb + g * 4 + 2] + bv;
        o4.w = LdsF[m][nb + g * 4 + 3] + bv;
        *(float4*)(dst + g * 4) = o4;
    }
}

extern "C" void kernel_launch(void* const* d_in, const int* in_sizes, int n_in,
                              void* d_out, int out_size, void* d_ws, size_t ws_size,
                              hipStream_t stream) {
    const float* x     = (const float*)d_in[0];
    const float* w_qkv = (const float*)d_in[1];
    const float* w_out = (const float*)d_in[2];
    const float* b_out = (const float*)d_in[3];
    float* y = (float*)d_out;

    // workspace 20 MiB: Qp, Kp, Vp, Oth, Otl (4 MiB each)
    char* base = (char*)d_ws;
    unsigned short* Qp  = (unsigned short*)base;
    unsigned short* Kp  = Qp + (size_t)16 * N_TOK * 32;
    unsigned short* Vp  = Kp + (size_t)16 * N_TOK * 32;
    unsigned short* Oth = Vp + (size_t)16 * N_TOK * 32;
    unsigned short* Otl = Oth + (size_t)BATCH * N_TOK * 128;

    gemm1_fused<<<dim3(64, 6, BATCH), dim3(256), 0, stream>>>(
        w_qkv, x, Qp, Kp, Vp);
    attn_fused<<<dim3(64, 16), dim3(512), 0, stream>>>(Qp, Kp, Vp, Oth, Otl);
    gemm2_fused<<<dim3(64, 4, BATCH), dim3(256), 0, stream>>>(
        w_out, Oth, Otl, b_out, y);
}

// Round 6
// 152.509 us; speedup vs baseline: 1.0958x; 1.0958x over previous
//
#include <hip/hip_runtime.h>

#define N_TOK 4096
#define BATCH 4

typedef __attribute__((ext_vector_type(8))) short short8;
typedef __attribute__((ext_vector_type(4))) float floatx4;

// Pack two floats to packed bf16 pair (round-half-away): 3 VALU ops.
__device__ __forceinline__ unsigned pack_rnd(float a, float b) {
    unsigned ra = __float_as_uint(a) + 0x8000u;
    unsigned rb = __float_as_uint(b) + 0x8000u;
    return __builtin_amdgcn_perm(rb, ra, 0x07060302u);
}

// Split two floats into bf16 hi-pair and lo-pair.
__device__ __forceinline__ void split_pack(float a, float b,
                                           unsigned &ph, unsigned &pl) {
    unsigned ra = __float_as_uint(a) + 0x8000u;
    unsigned rb = __float_as_uint(b) + 0x8000u;
    ph = __builtin_amdgcn_perm(rb, ra, 0x07060302u);
    float la = a - __uint_as_float(ra & 0xffff0000u);
    float lb = b - __uint_as_float(rb & 0xffff0000u);
    pl = __builtin_amdgcn_perm(__float_as_uint(lb) + 0x8000u,
                               __float_as_uint(la) + 0x8000u, 0x07060302u);
}

__device__ __forceinline__ short8 mk_short8(unsigned p0, unsigned p1,
                                            unsigned p2, unsigned p3) {
    union { unsigned u[4]; short8 s; } c;
    c.u[0] = p0; c.u[1] = p1; c.u[2] = p2; c.u[3] = p3;
    return c.s;
}

// Convert 8 consecutive fp32 (two float4) into hi/lo short8 fragments.
__device__ __forceinline__ void cvt_frag(const float* src,
                                         short8 &hi, short8 &lo) {
    float4 w0 = *(const float4*)src;
    float4 w1 = *(const float4*)(src + 4);
    unsigned ph[4], pl[4];
    split_pack(w0.x, w0.y, ph[0], pl[0]);
    split_pack(w0.z, w0.w, ph[1], pl[1]);
    split_pack(w1.x, w1.y, ph[2], pl[2]);
    split_pack(w1.z, w1.w, ph[3], pl[3]);
    hi = mk_short8(ph[0], ph[1], ph[2], ph[3]);
    lo = mk_short8(pl[0], pl[1], pl[2], pl[3]);
}

__device__ __forceinline__ float fast_exp2(float x) {
#if __has_builtin(__builtin_amdgcn_exp2f)
    return __builtin_amdgcn_exp2f(x);
#else
    return exp2f(x);
#endif
}

// ---------------------------------------------------------------------------
// QKV GEMM.  NEW this round: x is loaded DIRECTLY TRANSPOSED from global
// (8 c-strided dword loads per thread = 8 coalesced 256B wave-transactions),
// split in-register, stored once to LDS [n][40].  This deletes the fp32 LDS
// tile + the transpose phase + one barrier per 32-k chunk (3->2 barriers,
// 12->4 LDS ops/thread/chunk).  LDS content entering the MFMAs is
// byte-identical to the round-3 kernel -> absmax must be 3.051758e-05.
// LDS 20480 B.  Grid (64 n, 6 m, 4 b), 256 threads.
// ---------------------------------------------------------------------------
__global__ __launch_bounds__(256) void gemm1_fused(
    const float* __restrict__ wq, const float* __restrict__ x,
    unsigned short* __restrict__ Qp, unsigned short* __restrict__ Kp,
    unsigned short* __restrict__ Vp)
{
    const int N = N_TOK;
    const int b = blockIdx.z;
    const int row0 = blockIdx.y * 64;
    const int col0 = blockIdx.x * 64;
    const int t = threadIdx.x;
    const int wave = t >> 6, lane = t & 63;
    const int l16 = lane & 15, quad = lane >> 4;
    const int msub0 = (wave & 1) * 32, nsub0 = (wave >> 1) * 32;

    // WsH @0, WsL @2560, XsH @5120, XsL @7680 (short offsets); 20480 B.
    __shared__ __align__(16) char smem[20480];
    unsigned short* WsH = (unsigned short*)smem;
    unsigned short* WsL = (unsigned short*)(smem + 5120);
    unsigned short* XsH = (unsigned short*)(smem + 10240);
    unsigned short* XsL = (unsigned short*)(smem + 15360);

    floatx4 acc[2][2] = {};

    const int wm = t >> 2, wk = (t & 3) * 8;       // W load role
    const int xn = t & 63, xc8 = (t >> 6) * 8;     // x transposed-load role

    for (int kc = 0; kc < 8; ++kc) {
        __syncthreads();
        {   // W chunk: coalesced load + in-reg split -> LDS [m][40] hi/lo
            const float* wsrc = wq + (size_t)(row0 + wm) * 256 + kc * 32 + wk;
            float4 w0 = *(const float4*)wsrc;
            float4 w1 = *(const float4*)(wsrc + 4);
            unsigned ph[4], pl[4];
            split_pack(w0.x, w0.y, ph[0], pl[0]);
            split_pack(w0.z, w0.w, ph[1], pl[1]);
            split_pack(w1.x, w1.y, ph[2], pl[2]);
            split_pack(w1.z, w1.w, ph[3], pl[3]);
            *(uint4*)(WsH + wm * 40 + wk) = *(uint4*)ph;
            *(uint4*)(WsL + wm * 40 + wk) = *(uint4*)pl;
        }
        {   // x chunk: transposed loads (coalesced in n) + split -> [n][40]
            const float* xsrc = x + ((size_t)b * 256 + kc * 32 + xc8) * N
                                  + col0 + xn;
            float v[8];
#pragma unroll
            for (int i = 0; i < 8; ++i) v[i] = xsrc[(size_t)i * N];
            unsigned ph[4], pl[4];
            split_pack(v[0], v[1], ph[0], pl[0]);
            split_pack(v[2], v[3], ph[1], pl[1]);
            split_pack(v[4], v[5], ph[2], pl[2]);
            split_pack(v[6], v[7], ph[3], pl[3]);
            *(uint4*)(XsH + xn * 40 + xc8) = *(uint4*)ph;
            *(uint4*)(XsL + xn * 40 + xc8) = *(uint4*)pl;
        }
        __syncthreads();
        short8 ah0 = *(const short8*)(WsH + (msub0 + l16) * 40 + quad * 8);
        short8 ah1 = *(const short8*)(WsH + (msub0 + 16 + l16) * 40 + quad * 8);
        short8 al0 = *(const short8*)(WsL + (msub0 + l16) * 40 + quad * 8);
        short8 al1 = *(const short8*)(WsL + (msub0 + 16 + l16) * 40 + quad * 8);
        short8 bh0 = *(const short8*)(XsH + (nsub0 + l16) * 40 + quad * 8);
        short8 bh1 = *(const short8*)(XsH + (nsub0 + 16 + l16) * 40 + quad * 8);
        short8 bl0 = *(const short8*)(XsL + (nsub0 + l16) * 40 + quad * 8);
        short8 bl1 = *(const short8*)(XsL + (nsub0 + 16 + l16) * 40 + quad * 8);
        acc[0][0] = __builtin_amdgcn_mfma_f32_16x16x32_bf16(ah0, bh0, acc[0][0], 0, 0, 0);
        acc[0][1] = __builtin_amdgcn_mfma_f32_16x16x32_bf16(ah0, bh1, acc[0][1], 0, 0, 0);
        acc[1][0] = __builtin_amdgcn_mfma_f32_16x16x32_bf16(ah1, bh0, acc[1][0], 0, 0, 0);
        acc[1][1] = __builtin_amdgcn_mfma_f32_16x16x32_bf16(ah1, bh1, acc[1][1], 0, 0, 0);
        acc[0][0] = __builtin_amdgcn_mfma_f32_16x16x32_bf16(ah0, bl0, acc[0][0], 0, 0, 0);
        acc[0][1] = __builtin_amdgcn_mfma_f32_16x16x32_bf16(ah0, bl1, acc[0][1], 0, 0, 0);
        acc[1][0] = __builtin_amdgcn_mfma_f32_16x16x32_bf16(ah1, bl0, acc[1][0], 0, 0, 0);
        acc[1][1] = __builtin_amdgcn_mfma_f32_16x16x32_bf16(ah1, bl1, acc[1][1], 0, 0, 0);
        acc[0][0] = __builtin_amdgcn_mfma_f32_16x16x32_bf16(al0, bh0, acc[0][0], 0, 0, 0);
        acc[0][1] = __builtin_amdgcn_mfma_f32_16x16x32_bf16(al0, bh1, acc[0][1], 0, 0, 0);
        acc[1][0] = __builtin_amdgcn_mfma_f32_16x16x32_bf16(al1, bh0, acc[1][0], 0, 0, 0);
        acc[1][1] = __builtin_amdgcn_mfma_f32_16x16x32_bf16(al1, bh1, acc[1][1], 0, 0, 0);
    }

    __syncthreads();
    const int region = row0 >> 7;   // 0=Q, 1=K, 2=V
    if (region == 2) {
        float (*LdsF)[68] = (float(*)[68])smem;
#pragma unroll
        for (int i = 0; i < 2; ++i)
#pragma unroll
            for (int j = 0; j < 2; ++j) {
                const int m = msub0 + i * 16 + quad * 4;
                const int n = nsub0 + j * 16 + l16;
#pragma unroll
                for (int r = 0; r < 4; ++r) LdsF[m + r][n] = acc[i][j][r];
            }
        __syncthreads();
        const int m = t >> 2, nb2 = (t & 3) * 16;
        const int vrow = b * 128 + (row0 - 256) + m;
        unsigned pk[8];
#pragma unroll
        for (int q = 0; q < 8; ++q)
            pk[q] = pack_rnd(LdsF[m][nb2 + 2 * q], LdsF[m][nb2 + 2 * q + 1]);
        unsigned short* dst = Vp + (size_t)vrow * N + col0 + nb2;
        *(uint4*)&dst[0] = *(uint4*)&pk[0];
        *(uint4*)&dst[8] = *(uint4*)&pk[4];
    } else {
        unsigned short (*LdsT)[68] = (unsigned short(*)[68])smem;
        const float sc = region ? 1.0f
                                : (0.17677669529663687f * 1.4426950408889634f);
#pragma unroll
        for (int i = 0; i < 2; ++i)
#pragma unroll
            for (int j = 0; j < 2; ++j) {
                const int m = msub0 + i * 16 + quad * 4;
                const int n = nsub0 + j * 16 + l16;
                uint2 pr;
                pr.x = pack_rnd(acc[i][j][0] * sc, acc[i][j][1] * sc);
                pr.y = pack_rnd(acc[i][j][2] * sc, acc[i][j][3] * sc);
                *(uint2*)&LdsT[n][m] = pr;
            }
        __syncthreads();
        const int n = t & 63, hb = (t >> 6) & 1, dh = t >> 7;
        const int h = ((row0 & 127) >> 5) + hb;
        const int m0 = hb * 32 + dh * 16;
        unsigned tmp[8];
        *(uint2*)&tmp[0] = *(const uint2*)&LdsT[n][m0];
        *(uint2*)&tmp[2] = *(const uint2*)&LdsT[n][m0 + 4];
        *(uint2*)&tmp[4] = *(const uint2*)&LdsT[n][m0 + 8];
        *(uint2*)&tmp[6] = *(const uint2*)&LdsT[n][m0 + 12];
        unsigned short* dst = (region ? Kp : Qp) +
            ((size_t)(b * 4 + h) * N + col0 + n) * 32 + dh * 16;
        *(uint4*)&dst[0] = *(uint4*)&tmp[0];
        *(uint4*)&dst[8] = *(uint4*)&tmp[4];
    }
}

// ---------------------------------------------------------------------------
// MFMA flash attention -- EXACT round-3 form (proven 55.8 us).  Q-tile 128,
// grid (32 i0, 16 bh).  Round-5 measured: halving the Q-tile raised
// occupancy 31->49% but cost +10 us (staging-bound, not latency-bound).
// ---------------------------------------------------------------------------
__global__ __launch_bounds__(512) void attn_fused(
    const unsigned short* __restrict__ Qp,
    const unsigned short* __restrict__ Kp,
    const unsigned short* __restrict__ Vp,
    unsigned short* __restrict__ Oth, unsigned short* __restrict__ Otl)
{
    const int N = N_TOK;
    const int bh = blockIdx.y;
    const int b = bh >> 2, h = bh & 3;
    const int i0 = blockIdx.x * 128;
    const int t = threadIdx.x;
    const int wave = t >> 6, lane = t & 63;
    const int l16 = lane & 15, quad = lane >> 4;
    const int team = wave >> 2, w4 = wave & 3;

    __shared__ __align__(16) char smem[38912];
    unsigned short* S = (unsigned short*)smem;

    short8 ones;
#pragma unroll
    for (int e = 0; e < 8; ++e) ones[e] = (short)0x3F80;

    short8 qh[2];
#pragma unroll
    for (int g = 0; g < 2; ++g)
        qh[g] = *(const short8*)(Qp +
            ((size_t)bh * N + i0 + w4 * 32 + g * 16 + l16) * 32 + quad * 8);

    floatx4 o[2][2] = {};
    floatx4 lacc[2] = {};

    const int st_k = t & 255;
    const int skey = st_k >> 2, sdp = (st_k & 3) * 8;
    const int sslot = (skey & 32) | ((skey & 4) << 2) | ((skey & 24) >> 1)
                    | (skey & 3);
    const int svd = st_k >> 3, svp = (st_k & 7) * 8;
    const unsigned short* kp0 = Kp + ((size_t)bh * N + skey) * 32 + sdp;
    const unsigned short* kp1 = kp0 + (size_t)2048 * 32;
    const unsigned short* vp0 = Vp + ((size_t)bh * 32 + svd) * N + svp;
    const unsigned short* vp1 = vp0 + 2048;

    short8 r0, r1;
    if (t < 256) { r0 = *(const short8*)kp0; r1 = *(const short8*)kp1; }
    else         { r0 = *(const short8*)vp0; r1 = *(const short8*)vp1; }
    if (t < 256) {
        *(short8*)(S + sslot * 40 + sdp) = r0;
        *(short8*)(S + 2560 + sslot * 40 + sdp) = r1;
    } else {
        *(short8*)(S + 10240 + svd * 72 + svp) = r0;
        *(short8*)(S + 10240 + 2304 + svd * 72 + svp) = r1;
    }
    kp0 += 64 * 32; kp1 += 64 * 32; vp0 += 64; vp1 += 64;
    if (t < 256) { r0 = *(const short8*)kp0; r1 = *(const short8*)kp1; }
    else         { r0 = *(const short8*)vp0; r1 = *(const short8*)vp1; }
    __syncthreads();

    for (int it = 0; it < 32; ++it) {
        const int cur = it & 1;
        if (it + 1 < 32) {
            const int nb = 1 - cur;
            if (t < 256) {
                *(short8*)(S + nb * 5120 + sslot * 40 + sdp) = r0;
                *(short8*)(S + nb * 5120 + 2560 + sslot * 40 + sdp) = r1;
            } else {
                *(short8*)(S + 10240 + nb * 4608 + svd * 72 + svp) = r0;
                *(short8*)(S + 10240 + nb * 4608 + 2304 + svd * 72 + svp) = r1;
            }
        }
        if (it + 2 < 32) {
            kp0 += 64 * 32; kp1 += 64 * 32; vp0 += 64; vp1 += 64;
            if (t < 256) { r0 = *(const short8*)kp0; r1 = *(const short8*)kp1; }
            else         { r0 = *(const short8*)vp0; r1 = *(const short8*)vp1; }
        }

        const unsigned short* Ksr = S + cur * 5120 + team * 2560;
        const unsigned short* Vsr = S + 10240 + cur * 4608 + team * 2304;

        short8 kh0 = *(const short8*)(Ksr + ( 0 + l16) * 40 + quad * 8);
        short8 kh1 = *(const short8*)(Ksr + (16 + l16) * 40 + quad * 8);
        short8 kh2 = *(const short8*)(Ksr + (32 + l16) * 40 + quad * 8);
        short8 kh3 = *(const short8*)(Ksr + (48 + l16) * 40 + quad * 8);
        short8 vh00 = *(const short8*)(Vsr + ( 0 + l16) * 72 +  0 + quad * 8);
        short8 vh01 = *(const short8*)(Vsr + (16 + l16) * 72 +  0 + quad * 8);
        short8 vh10 = *(const short8*)(Vsr + ( 0 + l16) * 72 + 32 + quad * 8);
        short8 vh11 = *(const short8*)(Vsr + (16 + l16) * 72 + 32 + quad * 8);

#pragma unroll
        for (int g = 0; g < 2; ++g) {
            const floatx4 z = {0.0f, 0.0f, 0.0f, 0.0f};
            floatx4 s0 = __builtin_amdgcn_mfma_f32_16x16x32_bf16(kh0, qh[g], z, 0, 0, 0);
            floatx4 s1 = __builtin_amdgcn_mfma_f32_16x16x32_bf16(kh1, qh[g], z, 0, 0, 0);
            floatx4 s2 = __builtin_amdgcn_mfma_f32_16x16x32_bf16(kh2, qh[g], z, 0, 0, 0);
            floatx4 s3 = __builtin_amdgcn_mfma_f32_16x16x32_bf16(kh3, qh[g], z, 0, 0, 0);
            short8 pf0 = mk_short8(
                pack_rnd(fast_exp2(s0[0]), fast_exp2(s0[1])),
                pack_rnd(fast_exp2(s0[2]), fast_exp2(s0[3])),
                pack_rnd(fast_exp2(s1[0]), fast_exp2(s1[1])),
                pack_rnd(fast_exp2(s1[2]), fast_exp2(s1[3])));
            o[g][0] = __builtin_amdgcn_mfma_f32_16x16x32_bf16(vh00, pf0, o[g][0], 0, 0, 0);
            o[g][1] = __builtin_amdgcn_mfma_f32_16x16x32_bf16(vh01, pf0, o[g][1], 0, 0, 0);
            lacc[g] = __builtin_amdgcn_mfma_f32_16x16x32_bf16(ones, pf0, lacc[g], 0, 0, 0);
            short8 pf1 = mk_short8(
                pack_rnd(fast_exp2(s2[0]), fast_exp2(s2[1])),
                pack_rnd(fast_exp2(s2[2]), fast_exp2(s2[3])),
                pack_rnd(fast_exp2(s3[0]), fast_exp2(s3[1])),
                pack_rnd(fast_exp2(s3[2]), fast_exp2(s3[3])));
            o[g][0] = __builtin_amdgcn_mfma_f32_16x16x32_bf16(vh10, pf1, o[g][0], 0, 0, 0);
            o[g][1] = __builtin_amdgcn_mfma_f32_16x16x32_bf16(vh11, pf1, o[g][1], 0, 0, 0);
            lacc[g] = __builtin_amdgcn_mfma_f32_16x16x32_bf16(ones, pf1, lacc[g], 0, 0, 0);
        }
        __syncthreads();
    }

    float (*OfB)[132] = (float(*)[132])smem;
    float* Lb = (float*)(smem + 16896);
    float (*OfA)[132] = (float(*)[132])(smem + 17408);

    if (team == 1) {
#pragma unroll
        for (int g = 0; g < 2; ++g) {
            const int q = w4 * 32 + g * 16 + l16;
#pragma unroll
            for (int half = 0; half < 2; ++half)
#pragma unroll
                for (int r = 0; r < 4; ++r)
                    OfB[half * 16 + quad * 4 + r][q] = o[g][half][r];
            if (quad == 0) Lb[q] = lacc[g][0];
        }
    }
    __syncthreads();
    if (team == 0) {
#pragma unroll
        for (int g = 0; g < 2; ++g) {
            const int q = w4 * 32 + g * 16 + l16;
            const float inv = 1.0f / (lacc[g][0] + Lb[q]);
#pragma unroll
            for (int half = 0; half < 2; ++half)
#pragma unroll
                for (int r = 0; r < 4; ++r) {
                    const int d = half * 16 + quad * 4 + r;
                    OfA[d][q] = (o[g][half][r] + OfB[d][q]) * inv;
                }
        }
    }
    __syncthreads();
    {
        const int q = t >> 2, db = (t & 3) * 8;
        unsigned ph[4], pl[4];
#pragma unroll
        for (int i = 0; i < 4; ++i)
            split_pack(OfA[db + 2 * i][q], OfA[db + 2 * i + 1][q], ph[i], pl[i]);
        const size_t off = ((size_t)b * N + i0 + q) * 128 + h * 32 + db;
        *(uint4*)(Oth + off) = *(uint4*)ph;
        *(uint4*)(Otl + off) = *(uint4*)pl;
    }
}

// ---------------------------------------------------------------------------
// Output GEMM, split-bf16 MFMA, LDS-staged B, inline-converted W (preloaded),
// + bias.  (round-3 proven form)
// ---------------------------------------------------------------------------
__global__ __launch_bounds__(256) void gemm2_fused(
    const float* __restrict__ wo,
    const unsigned short* __restrict__ Oth, const unsigned short* __restrict__ Otl,
    const float* __restrict__ bias, float* __restrict__ y)
{
    const int N = N_TOK;
    const int b = blockIdx.z;
    const int row0 = blockIdx.y * 64;
    const int col0 = blockIdx.x * 64;
    const int t = threadIdx.x;
    const int wave = t >> 6, lane = t & 63;
    const int l16 = lane & 15, quad = lane >> 4;
    const int msub0 = (wave & 1) * 32, nsub0 = (wave >> 1) * 32;

    __shared__ __align__(16) char smem[17408];
    unsigned short* BsH = (unsigned short*)smem;           // [64][40]
    unsigned short* BsL = (unsigned short*)(smem + 5120);  // [64][40]
    float (*LdsF)[68] = (float(*)[68])smem;                // epilogue reuse

    short8 ah[4][2], al[4][2];
#pragma unroll
    for (int kc = 0; kc < 4; ++kc)
#pragma unroll
        for (int r = 0; r < 2; ++r)
            cvt_frag(wo + (size_t)(row0 + msub0 + r * 16 + l16) * 128 +
                         kc * 32 + quad * 8,
                     ah[kc][r], al[kc][r]);

    const int srow = t >> 2, sk = (t & 3) * 8;
    const unsigned short* gH = Oth + ((size_t)b * N + col0 + srow) * 128 + sk;
    const unsigned short* gL = Otl + ((size_t)b * N + col0 + srow) * 128 + sk;

    floatx4 acc[2][2] = {};
#pragma unroll
    for (int kc = 0; kc < 4; ++kc) {
        short8 hreg = *(const short8*)(gH + kc * 32);
        short8 lreg = *(const short8*)(gL + kc * 32);
        __syncthreads();
        *(short8*)(BsH + srow * 40 + sk) = hreg;
        *(short8*)(BsL + srow * 40 + sk) = lreg;
        __syncthreads();
        short8 bh0 = *(const short8*)(BsH + (nsub0 + l16) * 40 + quad * 8);
        short8 bh1 = *(const short8*)(BsH + (nsub0 + 16 + l16) * 40 + quad * 8);
        short8 bl0 = *(const short8*)(BsL + (nsub0 + l16) * 40 + quad * 8);
        short8 bl1 = *(const short8*)(BsL + (nsub0 + 16 + l16) * 40 + quad * 8);
        acc[0][0] = __builtin_amdgcn_mfma_f32_16x16x32_bf16(ah[kc][0], bh0, acc[0][0], 0, 0, 0);
        acc[0][1] = __builtin_amdgcn_mfma_f32_16x16x32_bf16(ah[kc][0], bh1, acc[0][1], 0, 0, 0);
        acc[1][0] = __builtin_amdgcn_mfma_f32_16x16x32_bf16(ah[kc][1], bh0, acc[1][0], 0, 0, 0);
        acc[1][1] = __builtin_amdgcn_mfma_f32_16x16x32_bf16(ah[kc][1], bh1, acc[1][1], 0, 0, 0);
        acc[0][0] = __builtin_amdgcn_mfma_f32_16x16x32_bf16(ah[kc][0], bl0, acc[0][0], 0, 0, 0);
        acc[0][1] = __builtin_amdgcn_mfma_f32_16x16x32_bf16(ah[kc][0], bl1, acc[0][1], 0, 0, 0);
        acc[1][0] = __builtin_amdgcn_mfma_f32_16x16x32_bf16(ah[kc][1], bl0, acc[1][0], 0, 0, 0);
        acc[1][1] = __builtin_amdgcn_mfma_f32_16x16x32_bf16(ah[kc][1], bl1, acc[1][1], 0, 0, 0);
        acc[0][0] = __builtin_amdgcn_mfma_f32_16x16x32_bf16(al[kc][0], bh0, acc[0][0], 0, 0, 0);
        acc[0][1] = __builtin_amdgcn_mfma_f32_16x16x32_bf16(al[kc][0], bh1, acc[0][1], 0, 0, 0);
        acc[1][0] = __builtin_amdgcn_mfma_f32_16x16x32_bf16(al[kc][1], bh0, acc[1][0], 0, 0, 0);
        acc[1][1] = __builtin_amdgcn_mfma_f32_16x16x32_bf16(al[kc][1], bh1, acc[1][1], 0, 0, 0);
    }

    __syncthreads();
#pragma unroll
    for (int i = 0; i < 2; ++i)
#pragma unroll
        for (int j = 0; j < 2; ++j) {
            const int m = msub0 + i * 16 + quad * 4;
            const int n = nsub0 + j * 16 + l16;
#pragma unroll
            for (int r = 0; r < 4; ++r) LdsF[m + r][n] = acc[i][j][r];
        }
    __syncthreads();
    const int m = t >> 2, nb = (t & 3) * 16;
    const float bv = bias[row0 + m];
    float* dst = y + ((size_t)b * 256 + row0 + m) * N + col0 + nb;
#pragma unroll
    for (int g = 0; g < 4; ++g) {
        float4 o4;
        o4.x = LdsF[m][nb + g * 4 + 0] + bv;
        o4.y = LdsF[m][nb + g * 4 + 1] + bv;
        o4.z = LdsF[m][nb + g * 4 + 2] + bv;
        o4.w = LdsF[m][nb + g * 4 + 3] + bv;
        *(float4*)(dst + g * 4) = o4;
    }
}

extern "C" void kernel_launch(void* const* d_in, const int* in_sizes, int n_in,
                              void* d_out, int out_size, void* d_ws, size_t ws_size,
                              hipStream_t stream) {
    const float* x     = (const float*)d_in[0];
    const float* w_qkv = (const float*)d_in[1];
    const float* w_out = (const float*)d_in[2];
    const float* b_out = (const float*)d_in[3];
    float* y = (float*)d_out;

    // workspace 20 MiB: Qp, Kp, Vp, Oth, Otl (4 MiB each)
    char* base = (char*)d_ws;
    unsigned short* Qp  = (unsigned short*)base;
    unsigned short* Kp  = Qp + (size_t)16 * N_TOK * 32;
    unsigned short* Vp  = Kp + (size_t)16 * N_TOK * 32;
    unsigned short* Oth = Vp + (size_t)16 * N_TOK * 32;
    unsigned short* Otl = Oth + (size_t)BATCH * N_TOK * 128;

    gemm1_fused<<<dim3(64, 6, BATCH), dim3(256), 0, stream>>>(
        w_qkv, x, Qp, Kp, Vp);
    attn_fused<<<dim3(32, 16), dim3(512), 0, stream>>>(Qp, Kp, Vp, Oth, Otl);
    gemm2_fused<<<dim3(64, 4, BATCH), dim3(256), 0, stream>>>(
        w_out, Oth, Otl, b_out, y);
}